// Round 1
// baseline (557.679 us; speedup 1.0000x reference)
//
#include <hip/hip_runtime.h>
#include <hip/hip_bf16.h>
#include <math.h>

#define BB 16
#define SS 512
#define DMM 256
#define HH 8
#define DFF 32
#define KIDX 5

// ---------------------------------------------------------------------------
// GEMM: Y = X @ W^T + bias.  X:(M,256) row-major, W:(256,256) row-major (N,K).
// headsLayout=1 -> Y stored as (B,H,S,DF); headsLayout=0 -> Y stored (M,256).
// 64x64 tile, 256 threads, 4x4 register tile per thread, BK=16.
// ---------------------------------------------------------------------------
__global__ __launch_bounds__(256) void gemm_bias_kernel(
    const float* __restrict__ X,
    const float* __restrict__ W,
    const float* __restrict__ bias,
    float* __restrict__ Y,
    int headsLayout)
{
  __shared__ float As[16][64];
  __shared__ float Bs[16][65];
  const int tid = threadIdx.x;
  const int tx = tid & 15;
  const int ty = tid >> 4;
  const int m0 = blockIdx.x * 64;
  const int n0 = blockIdx.y * 64;
  float acc[4][4] = {};
  for (int k0 = 0; k0 < DMM; k0 += 16) {
    {
      const int r  = tid >> 2;         // 0..63
      const int c4 = (tid & 3) << 2;   // 0,4,8,12
      const float4 a = *reinterpret_cast<const float4*>(&X[(size_t)(m0 + r) * DMM + k0 + c4]);
      As[c4 + 0][r] = a.x; As[c4 + 1][r] = a.y; As[c4 + 2][r] = a.z; As[c4 + 3][r] = a.w;
      const float4 w = *reinterpret_cast<const float4*>(&W[(size_t)(n0 + r) * DMM + k0 + c4]);
      Bs[c4 + 0][r] = w.x; Bs[c4 + 1][r] = w.y; Bs[c4 + 2][r] = w.z; Bs[c4 + 3][r] = w.w;
    }
    __syncthreads();
    #pragma unroll
    for (int k = 0; k < 16; ++k) {
      float a[4], b[4];
      #pragma unroll
      for (int i = 0; i < 4; ++i) a[i] = As[k][ty * 4 + i];
      #pragma unroll
      for (int j = 0; j < 4; ++j) b[j] = Bs[k][tx * 4 + j];
      #pragma unroll
      for (int i = 0; i < 4; ++i)
        #pragma unroll
        for (int j = 0; j < 4; ++j)
          acc[i][j] += a[i] * b[j];
    }
    __syncthreads();
  }
  #pragma unroll
  for (int i = 0; i < 4; ++i) {
    const int m = m0 + ty * 4 + i;
    #pragma unroll
    for (int j = 0; j < 4; ++j) {
      const int n = n0 + tx * 4 + j;
      const float v = acc[i][j] + bias[n];
      if (headsLayout) {
        const int b = m >> 9;           // m / S
        const int s = m & (SS - 1);
        const int h = n >> 5;           // n / DF
        const int d = n & (DFF - 1);
        Y[(((size_t)b * HH + h) * SS + s) * DFF + d] = v;
      } else {
        Y[(size_t)m * DMM + n] = v;
      }
    }
  }
}

// ---------------------------------------------------------------------------
// Attention: one wave (64 lanes) per (b,h,qrow). Each lane owns 8 column
// slots (col = lane + 64*slot). f32 softmax, 5-round max-extraction for the
// top-5 threshold (counting duplicates, matching lax.top_k), re-softmax over
// kept entries, zero_pad of row 0, full attn row written (incl. zeros),
// sparse ctx accumulation into concat (B,S,DM) layout.
// ---------------------------------------------------------------------------
__global__ __launch_bounds__(256) void attn_kernel(
    const float* __restrict__ qh,
    const float* __restrict__ kh,
    const float* __restrict__ vh,
    const int* __restrict__ zp,
    float* __restrict__ attn,
    float* __restrict__ concat)
{
  const int lane = threadIdx.x & 63;
  const int wave = threadIdx.x >> 6;
  const int row  = blockIdx.x * 4 + wave;   // 0 .. B*H*S-1
  const int qrow = row & (SS - 1);
  const int bh   = row >> 9;                // b*H + h
  const int b    = bh >> 3;
  const int h    = bh & 7;
  const int ncols = qrow + 1;
  const float scale = 0.17677669529663688f;  // 1/sqrt(32)

  float qreg[DFF];
  {
    const float* qp = qh + ((size_t)bh * SS + qrow) * DFF;
    #pragma unroll
    for (int i = 0; i < DFF / 4; ++i) {
      const float4 t = *reinterpret_cast<const float4*>(qp + i * 4);
      qreg[i*4+0] = t.x; qreg[i*4+1] = t.y; qreg[i*4+2] = t.z; qreg[i*4+3] = t.w;
    }
  }

  const float* kb = kh + (size_t)bh * SS * DFF;
  float p[8];
  #pragma unroll
  for (int s2 = 0; s2 < 8; ++s2) {
    const int col = lane + 64 * s2;
    float v = -INFINITY;
    if (col < ncols) {
      const float* kp = kb + (size_t)col * DFF;
      float dot = 0.f;
      #pragma unroll
      for (int d4 = 0; d4 < DFF; d4 += 4) {
        const float4 kv = *reinterpret_cast<const float4*>(kp + d4);
        dot += qreg[d4]*kv.x + qreg[d4+1]*kv.y + qreg[d4+2]*kv.z + qreg[d4+3]*kv.w;
      }
      v = dot * scale;
    }
    p[s2] = v;
  }

  // softmax (f32, exp(x - max)/sum — matches jax.nn.softmax)
  float m = p[0];
  #pragma unroll
  for (int s2 = 1; s2 < 8; ++s2) m = fmaxf(m, p[s2]);
  #pragma unroll
  for (int off = 32; off >= 1; off >>= 1) m = fmaxf(m, __shfl_xor(m, off, 64));
  float sum = 0.f;
  #pragma unroll
  for (int s2 = 0; s2 < 8; ++s2) {
    const float e = (p[s2] == -INFINITY) ? 0.f : expf(p[s2] - m);
    p[s2] = e;
    sum += e;
  }
  #pragma unroll
  for (int off = 32; off >= 1; off >>= 1) sum += __shfl_xor(sum, off, 64);
  const float inv = 1.0f / sum;
  #pragma unroll
  for (int s2 = 0; s2 < 8; ++s2) p[s2] *= inv;   // invalid slots -> 0

  float neww[8];
  if (qrow > KIDX) {
    // top-5 threshold via 5 rounds of (max value, min index) extraction
    float pv[8];
    #pragma unroll
    for (int s2 = 0; s2 < 8; ++s2) {
      const int col = lane + 64 * s2;
      pv[s2] = (col < ncols) ? p[s2] : -INFINITY;
    }
    float thr = 0.f, m1 = 0.f;
    #pragma unroll
    for (int t = 0; t < KIDX; ++t) {
      float bv = -INFINITY;
      int   bi = 0x7fffffff;
      #pragma unroll
      for (int s2 = 0; s2 < 8; ++s2) {
        if (pv[s2] > bv) { bv = pv[s2]; bi = lane + 64 * s2; }
      }
      #pragma unroll
      for (int off = 32; off >= 1; off >>= 1) {
        const float ov = __shfl_xor(bv, off, 64);
        const int   oi = __shfl_xor(bi, off, 64);
        if (ov > bv || (ov == bv && oi < bi)) { bv = ov; bi = oi; }
      }
      if (t == 0) m1 = bv;
      thr = bv;
      const int osl = bi >> 6;
      if ((bi & 63) == lane) {
        #pragma unroll
        for (int s2 = 0; s2 < 8; ++s2) if (s2 == osl) pv[s2] = -INFINITY;
      }
    }
    // keep where p - thr >= 0 (reference comparison), re-softmax with max=m1
    float nsum = 0.f;
    #pragma unroll
    for (int s2 = 0; s2 < 8; ++s2) {
      const int col = lane + 64 * s2;
      float e = 0.f;
      if (col < ncols && (p[s2] - thr >= 0.f)) e = expf(p[s2] - m1);
      neww[s2] = e;
      nsum += e;
    }
    #pragma unroll
    for (int off = 32; off >= 1; off >>= 1) nsum += __shfl_xor(nsum, off, 64);
    const float ninv = 1.0f / nsum;
    #pragma unroll
    for (int s2 = 0; s2 < 8; ++s2) neww[s2] *= ninv;
  } else {
    #pragma unroll
    for (int s2 = 0; s2 < 8; ++s2) neww[s2] = p[s2];
  }

  if (qrow == 0 && *zp != 0) {
    #pragma unroll
    for (int s2 = 0; s2 < 8; ++s2) neww[s2] = 0.f;
  }

  // write the full attn row (zeros included — d_out is poisoned)
  {
    float* arow = attn + ((size_t)bh * SS + qrow) * SS;
    #pragma unroll
    for (int s2 = 0; s2 < 8; ++s2) arow[lane + 64 * s2] = neww[s2];
  }

  // ctx row = sum over kept cols of w * vh[col][:], exploiting sparsity.
  {
    const float* vb = vh + (size_t)bh * SS * DFF;
    const int d = lane & 31;
    float acc = 0.f;
    #pragma unroll
    for (int s2 = 0; s2 < 8; ++s2) {
      unsigned long long msk = __ballot(neww[s2] != 0.f);
      while (msk) {
        const int src = __ffsll(msk) - 1;
        msk &= msk - 1;
        const float w = __shfl(neww[s2], src, 64);
        acc += w * vb[(size_t)(src + 64 * s2) * DFF + d];
      }
    }
    if (lane < 32)
      concat[((size_t)b * SS + qrow) * DMM + h * DFF + d] = acc;
  }
}

extern "C" void kernel_launch(void* const* d_in, const int* in_sizes, int n_in,
                              void* d_out, int out_size, void* d_ws, size_t ws_size,
                              hipStream_t stream) {
  const float* q  = (const float*)d_in[0];
  const float* k  = (const float*)d_in[1];
  const float* v  = (const float*)d_in[2];
  // d_in[3] = mask (tril, hardcoded causal)
  const int*   zp = (const int*)d_in[4];
  const float* Wk = (const float*)d_in[5];
  const float* bk = (const float*)d_in[6];
  const float* Wv = (const float*)d_in[7];
  const float* bv = (const float*)d_in[8];
  const float* Wo = (const float*)d_in[9];
  const float* bo = (const float*)d_in[10];

  float* ws     = (float*)d_ws;
  float* qh     = ws;                 // (B,H,S,DF) 2,097,152 floats
  float* khp    = ws + 2097152;       // (B,H,S,DF)
  float* vhp    = ws + 4194304;       // (B,H,S,DF)
  float* concat = ws + 6291456;       // (B,S,DM)

  float* outp  = (float*)d_out;                       // (B,S,DM)
  float* attnp = outp + (size_t)BB * SS * DMM;        // (B,H,S,S)

  const dim3 gg(128, 4);
  gemm_bias_kernel<<<gg, 256, 0, stream>>>(q, Wk, bk, qh, 1);
  gemm_bias_kernel<<<gg, 256, 0, stream>>>(k, Wk, bk, khp, 1);
  gemm_bias_kernel<<<gg, 256, 0, stream>>>(v, Wv, bv, vhp, 1);
  attn_kernel<<<dim3(BB * HH * SS / 4), 256, 0, stream>>>(qh, khp, vhp, zp, attnp, concat);
  gemm_bias_kernel<<<gg, 256, 0, stream>>>(concat, Wo, bo, outp, 0);
}

// Round 3
// 348.052 us; speedup vs baseline: 1.6023x; 1.6023x over previous
//
#include <hip/hip_runtime.h>
#include <hip/hip_bf16.h>
#include <math.h>

#define BB 16
#define SS 512
#define DMM 256
#define HH 8
#define DFF 32
#define KIDX 5

// ---------------------------------------------------------------------------
// GEMM body: Y = X @ W^T + bias. X:(M,256), W:(256,256) row-major (N,K).
// 64x64 tile, 256 threads, 4x4 reg tile, BK=16, register-prefetch pipeline.
// heads=1 -> Y stored as (B,H,S,DF); heads=0 -> Y stored (M,256).
// ---------------------------------------------------------------------------
__device__ __forceinline__ void gemm_body(
    const float* __restrict__ X, const float* __restrict__ W,
    const float* __restrict__ bias, float* __restrict__ Y, const bool heads)
{
  __shared__ float As[16][64];
  __shared__ float Bs[16][64];
  const int tid = threadIdx.x;
  const int tx = tid & 15;
  const int ty = (tid >> 4) & 15;
  const int m0 = blockIdx.x * 64;
  const int n0 = blockIdx.y * 64;
  const int r  = tid >> 2;          // 0..63
  const int c4 = (tid & 3) << 2;    // 0,4,8,12

  float4 ax = *reinterpret_cast<const float4*>(&X[(size_t)(m0 + r) * DMM + c4]);
  float4 wx = *reinterpret_cast<const float4*>(&W[(size_t)(n0 + r) * DMM + c4]);
  float acc[4][4] = {};

  for (int k0 = 0; k0 < DMM; k0 += 16) {
    As[c4 + 0][r] = ax.x; As[c4 + 1][r] = ax.y; As[c4 + 2][r] = ax.z; As[c4 + 3][r] = ax.w;
    Bs[c4 + 0][r] = wx.x; Bs[c4 + 1][r] = wx.y; Bs[c4 + 2][r] = wx.z; Bs[c4 + 3][r] = wx.w;
    __syncthreads();
    if (k0 + 16 < DMM) {
      ax = *reinterpret_cast<const float4*>(&X[(size_t)(m0 + r) * DMM + k0 + 16 + c4]);
      wx = *reinterpret_cast<const float4*>(&W[(size_t)(n0 + r) * DMM + k0 + 16 + c4]);
    }
    #pragma unroll
    for (int kk = 0; kk < 16; ++kk) {
      const float4 a4 = *reinterpret_cast<const float4*>(&As[kk][ty * 4]);
      const float4 b4 = *reinterpret_cast<const float4*>(&Bs[kk][tx * 4]);
      acc[0][0] += a4.x * b4.x; acc[0][1] += a4.x * b4.y; acc[0][2] += a4.x * b4.z; acc[0][3] += a4.x * b4.w;
      acc[1][0] += a4.y * b4.x; acc[1][1] += a4.y * b4.y; acc[1][2] += a4.y * b4.z; acc[1][3] += a4.y * b4.w;
      acc[2][0] += a4.z * b4.x; acc[2][1] += a4.z * b4.y; acc[2][2] += a4.z * b4.z; acc[2][3] += a4.z * b4.w;
      acc[3][0] += a4.w * b4.x; acc[3][1] += a4.w * b4.y; acc[3][2] += a4.w * b4.z; acc[3][3] += a4.w * b4.w;
    }
    __syncthreads();
  }
  #pragma unroll
  for (int i = 0; i < 4; ++i) {
    const int m = m0 + ty * 4 + i;
    #pragma unroll
    for (int j = 0; j < 4; ++j) {
      const int n = n0 + tx * 4 + j;
      const float v = acc[i][j] + bias[n];
      if (heads) {
        const int b = m >> 9;
        const int s = m & (SS - 1);
        const int h = n >> 5;
        const int d = n & (DFF - 1);
        Y[(((size_t)b * HH + h) * SS + s) * DFF + d] = v;
      } else {
        Y[(size_t)m * DMM + n] = v;
      }
    }
  }
}

// q/k/v projections in one launch (blockIdx.z selects); q and k both use Wk.
__global__ __launch_bounds__(256) void proj_kernel(
    const float* __restrict__ q, const float* __restrict__ k, const float* __restrict__ v,
    const float* __restrict__ Wk, const float* __restrict__ bk,
    const float* __restrict__ Wv, const float* __restrict__ bv,
    float* __restrict__ qh, float* __restrict__ kh, float* __restrict__ vh)
{
  const int z = blockIdx.z;
  const float* X = (z == 0) ? q : (z == 1) ? k : v;
  const float* W = (z == 2) ? Wv : Wk;
  const float* bias = (z == 2) ? bv : bk;
  float* Y = (z == 0) ? qh : (z == 1) ? kh : vh;
  gemm_body(X, W, bias, Y, true);
}

__global__ __launch_bounds__(256) void out_kernel(
    const float* __restrict__ X, const float* __restrict__ Wo,
    const float* __restrict__ bo, float* __restrict__ Y)
{
  gemm_body(X, Wo, bo, Y, false);
}

// ---------------------------------------------------------------------------
// Attention: block = 4 waves = 4 consecutive qrows of one (b,h). K staged per
// 64-col chunk in LDS as K^T [32][64] (conflict-free), next chunk prefetched
// into registers. Softmax / top-5 math identical to the passing round-1
// version. PV: ballot-ranked gather into per-wave LDS, then 8 independent
// V-row loads.
// ---------------------------------------------------------------------------
__global__ __launch_bounds__(256) void attn_kernel(
    const float* __restrict__ qh,
    const float* __restrict__ kh,
    const float* __restrict__ vh,
    const int* __restrict__ zp,
    float* __restrict__ attn,
    float* __restrict__ concat)
{
  __shared__ float Ksh[DFF][64];     // K^T chunk: [d][col]
  __shared__ float ws_w[4][8];
  __shared__ int   ws_c[4][8];

  const int tid  = threadIdx.x;
  const int lane = tid & 63;
  const int wave = tid >> 6;
  const int grp  = blockIdx.x;        // 0..16383
  const int bh   = grp >> 7;          // 128 row-groups per (b,h)
  const int base = (grp & 127) << 2;
  const int qrow = base + wave;
  const int b    = bh >> 3;
  const int h    = bh & 7;
  const int ncols = qrow + 1;
  const float scale = 0.17677669529663688f;  // 1/sqrt(32)

  const float* kb = kh + (size_t)bh * SS * DFF;
  const float* vb = vh + (size_t)bh * SS * DFF;

  // q row into registers (uniform across the wave's lanes)
  float qreg[DFF];
  {
    const float* qp = qh + ((size_t)bh * SS + qrow) * DFF;
    #pragma unroll
    for (int i = 0; i < DFF / 4; ++i) {
      const float4 t = *reinterpret_cast<const float4*>(qp + i * 4);
      qreg[i*4+0] = t.x; qreg[i*4+1] = t.y; qreg[i*4+2] = t.z; qreg[i*4+3] = t.w;
    }
  }

  const int nch  = ((base + 3) >> 6) + 1;   // chunks this block stages
  const int mych = qrow >> 6;               // last chunk this wave uses

  // staging assignment: col = tid&63, d-block = (tid>>6)*8
  const int scol = tid & 63;
  const int sd0  = (tid >> 6) << 3;

  float p[8];
  #pragma unroll
  for (int i = 0; i < 8; ++i) p[i] = -INFINITY;

  const float* kp0 = kb + (size_t)scol * DFF + sd0;
  float4 r0 = *reinterpret_cast<const float4*>(kp0);
  float4 r1 = *reinterpret_cast<const float4*>(kp0 + 4);

  for (int c = 0; c < nch; ++c) {
    Ksh[sd0 + 0][scol] = r0.x; Ksh[sd0 + 1][scol] = r0.y;
    Ksh[sd0 + 2][scol] = r0.z; Ksh[sd0 + 3][scol] = r0.w;
    Ksh[sd0 + 4][scol] = r1.x; Ksh[sd0 + 5][scol] = r1.y;
    Ksh[sd0 + 6][scol] = r1.z; Ksh[sd0 + 7][scol] = r1.w;
    __syncthreads();
    if (c + 1 < nch) {
      const float* kp = kb + (size_t)(((c + 1) << 6) + scol) * DFF + sd0;
      r0 = *reinterpret_cast<const float4*>(kp);
      r1 = *reinterpret_cast<const float4*>(kp + 4);
    }
    if (c <= mych) {
      const int col = (c << 6) + lane;
      float da = 0.f, db = 0.f;
      #pragma unroll
      for (int d = 0; d < DFF; d += 2) {
        da += Ksh[d    ][lane] * qreg[d];
        db += Ksh[d + 1][lane] * qreg[d + 1];
      }
      if (col < ncols) p[c] = (da + db) * scale;
    }
    __syncthreads();
  }

  // ---- softmax (identical math/order to round 1) ----
  float m = p[0];
  #pragma unroll
  for (int s2 = 1; s2 < 8; ++s2) m = fmaxf(m, p[s2]);
  #pragma unroll
  for (int off = 32; off >= 1; off >>= 1) m = fmaxf(m, __shfl_xor(m, off, 64));
  float sum = 0.f;
  #pragma unroll
  for (int s2 = 0; s2 < 8; ++s2) {
    const float e = (p[s2] == -INFINITY) ? 0.f : expf(p[s2] - m);
    p[s2] = e;
    sum += e;
  }
  #pragma unroll
  for (int off = 32; off >= 1; off >>= 1) sum += __shfl_xor(sum, off, 64);
  const float inv = 1.0f / sum;
  #pragma unroll
  for (int s2 = 0; s2 < 8; ++s2) p[s2] *= inv;

  // ---- top-5 threshold + re-softmax (identical to round 1) ----
  float neww[8];
  if (qrow > KIDX) {
    float pv[8];
    #pragma unroll
    for (int s2 = 0; s2 < 8; ++s2) {
      const int col = lane + (s2 << 6);
      pv[s2] = (col < ncols) ? p[s2] : -INFINITY;
    }
    float thr = 0.f, m1 = 0.f;
    #pragma unroll
    for (int t = 0; t < KIDX; ++t) {
      float bv = -INFINITY;
      int   bi = 0x7fffffff;
      #pragma unroll
      for (int s2 = 0; s2 < 8; ++s2) {
        if (pv[s2] > bv) { bv = pv[s2]; bi = lane + (s2 << 6); }
      }
      #pragma unroll
      for (int off = 32; off >= 1; off >>= 1) {
        const float ov = __shfl_xor(bv, off, 64);
        const int   oi = __shfl_xor(bi, off, 64);
        if (ov > bv || (ov == bv && oi < bi)) { bv = ov; bi = oi; }
      }
      if (t == 0) m1 = bv;
      thr = bv;
      const int osl = bi >> 6;
      if ((bi & 63) == lane) {
        #pragma unroll
        for (int s2 = 0; s2 < 8; ++s2) if (s2 == osl) pv[s2] = -INFINITY;
      }
    }
    float nsum = 0.f;
    #pragma unroll
    for (int s2 = 0; s2 < 8; ++s2) {
      const int col = lane + (s2 << 6);
      float e = 0.f;
      if (col < ncols && (p[s2] - thr >= 0.f)) e = expf(p[s2] - m1);
      neww[s2] = e;
      nsum += e;
    }
    #pragma unroll
    for (int off = 32; off >= 1; off >>= 1) nsum += __shfl_xor(nsum, off, 64);
    const float ninv = 1.0f / nsum;
    #pragma unroll
    for (int s2 = 0; s2 < 8; ++s2) neww[s2] *= ninv;
  } else {
    #pragma unroll
    for (int s2 = 0; s2 < 8; ++s2) neww[s2] = p[s2];
  }

  if (qrow == 0 && *zp != 0) {
    #pragma unroll
    for (int s2 = 0; s2 < 8; ++s2) neww[s2] = 0.f;
  }

  // write full attn row
  {
    float* arow = attn + ((size_t)bh * SS + qrow) * SS;
    #pragma unroll
    for (int s2 = 0; s2 < 8; ++s2) arow[lane + (s2 << 6)] = neww[s2];
  }

  // ---- PV: rank kept columns into per-wave LDS, then parallel loads ----
  {
    unsigned long long msks[8];
    #pragma unroll
    for (int s2 = 0; s2 < 8; ++s2) msks[s2] = __ballot(neww[s2] != 0.f);
    int rbase = 0;
    #pragma unroll
    for (int s2 = 0; s2 < 8; ++s2) {
      const unsigned long long msk = msks[s2];
      const int myr = rbase + __popcll(msk & ((1ull << lane) - 1ull));
      if (((msk >> lane) & 1ull) && myr < 8) {
        ws_w[wave][myr] = neww[s2];
        ws_c[wave][myr] = (s2 << 6) | lane;
      }
      rbase += __popcll(msk);
    }
    const int nk = rbase;
    if (lane < 8 && lane >= nk) { ws_w[wave][lane] = 0.f; ws_c[wave][lane] = 0; }

    const int dd = lane & 31;
    float accv = 0.f;
    if (nk <= 8) {
      #pragma unroll
      for (int i = 0; i < 8; ++i)
        accv += ws_w[wave][i] * vb[(size_t)ws_c[wave][i] * DFF + dd];
    } else {
      // tie-overflow fallback (practically never taken)
      #pragma unroll
      for (int s2 = 0; s2 < 8; ++s2) {
        unsigned long long msk = msks[s2];
        while (msk) {
          const int src = __ffsll(msk) - 1;
          msk &= msk - 1;
          accv += __shfl(neww[s2], src, 64) * vb[(size_t)(src + (s2 << 6)) * DFF + dd];
        }
      }
    }
    if (lane < 32)
      concat[((size_t)b * SS + qrow) * DMM + h * DFF + dd] = accv;
  }
}

extern "C" void kernel_launch(void* const* d_in, const int* in_sizes, int n_in,
                              void* d_out, int out_size, void* d_ws, size_t ws_size,
                              hipStream_t stream) {
  const float* q  = (const float*)d_in[0];
  const float* k  = (const float*)d_in[1];
  const float* v  = (const float*)d_in[2];
  const int*   zp = (const int*)d_in[4];
  const float* Wk = (const float*)d_in[5];
  const float* bk = (const float*)d_in[6];
  const float* Wv = (const float*)d_in[7];
  const float* bv = (const float*)d_in[8];
  const float* Wo = (const float*)d_in[9];
  const float* bo = (const float*)d_in[10];

  float* ws     = (float*)d_ws;
  float* qhp    = ws;                 // (B,H,S,DF)
  float* khp    = ws + 2097152;       // (B,H,S,DF)
  float* vhp    = ws + 4194304;       // (B,H,S,DF)
  float* concat = ws + 6291456;       // (B,S,DM)

  float* outp  = (float*)d_out;                       // (B,S,DM)
  float* attnp = outp + (size_t)BB * SS * DMM;        // (B,H,S,S)

  proj_kernel<<<dim3(128, 4, 3), 256, 0, stream>>>(q, k, v, Wk, bk, Wv, bv, qhp, khp, vhp);
  attn_kernel<<<dim3(BB * HH * SS / 4), 256, 0, stream>>>(qhp, khp, vhp, zp, attnp, concat);
  out_kernel<<<dim3(128, 4), 256, 0, stream>>>(concat, Wo, bo, outp);
}

// Round 4
// 333.731 us; speedup vs baseline: 1.6710x; 1.0429x over previous
//
#include <hip/hip_runtime.h>
#include <hip/hip_bf16.h>
#include <math.h>

#define BB 16
#define SS 512
#define DMM 256
#define HH 8
#define DFF 32
#define KIDX 5

// ---------------------------------------------------------------------------
// GEMM: Y = X @ W^T + bias. X:(M,256), W:(256,256) row-major (N,K).
// TM x 64 tile, 256 threads, (TM/16) x 4 reg tile, BK=32, reg-prefetch.
// HEADS=1 -> Y stored as (B,H,S,DF); HEADS=0 -> Y stored (M,256).
// K accumulated sequentially 0..255 (same order as prior passing rounds).
// ---------------------------------------------------------------------------
template<int TM, bool HEADS>
__device__ __forceinline__ void gemm_body(
    const float* __restrict__ X, const float* __restrict__ W,
    const float* __restrict__ bias, float* __restrict__ Y)
{
  constexpr int RM = TM / 16;     // rows per thread (8 or 4)
  constexpr int NA = TM / 32;     // float4 A-loads per thread (4 or 2)
  __shared__ float As[32][TM];
  __shared__ float Bs[32][64];
  const int tid = threadIdx.x;
  const int tx = tid & 15;
  const int ty = tid >> 4;
  const int m0 = blockIdx.x * TM;
  const int n0 = blockIdx.y * 64;

  float4 pa[NA], pb[2];
  #pragma unroll
  for (int i = 0; i < NA; ++i) {
    const int f = tid * NA + i;
    pa[i] = *reinterpret_cast<const float4*>(&X[(size_t)(m0 + (f >> 3)) * DMM + ((f & 7) << 2)]);
  }
  #pragma unroll
  for (int i = 0; i < 2; ++i) {
    const int f = tid * 2 + i;
    pb[i] = *reinterpret_cast<const float4*>(&W[(size_t)(n0 + (f >> 3)) * DMM + ((f & 7) << 2)]);
  }

  float acc[RM][4] = {};

  for (int k0 = 0; k0 < DMM; k0 += 32) {
    #pragma unroll
    for (int i = 0; i < NA; ++i) {
      const int f = tid * NA + i;
      const int ar = f >> 3, ac4 = (f & 7) << 2;
      As[ac4 + 0][ar] = pa[i].x; As[ac4 + 1][ar] = pa[i].y;
      As[ac4 + 2][ar] = pa[i].z; As[ac4 + 3][ar] = pa[i].w;
    }
    #pragma unroll
    for (int i = 0; i < 2; ++i) {
      const int f = tid * 2 + i;
      const int br = f >> 3, bc4 = (f & 7) << 2;
      Bs[bc4 + 0][br] = pb[i].x; Bs[bc4 + 1][br] = pb[i].y;
      Bs[bc4 + 2][br] = pb[i].z; Bs[bc4 + 3][br] = pb[i].w;
    }
    __syncthreads();
    if (k0 + 32 < DMM) {
      #pragma unroll
      for (int i = 0; i < NA; ++i) {
        const int f = tid * NA + i;
        pa[i] = *reinterpret_cast<const float4*>(&X[(size_t)(m0 + (f >> 3)) * DMM + k0 + 32 + ((f & 7) << 2)]);
      }
      #pragma unroll
      for (int i = 0; i < 2; ++i) {
        const int f = tid * 2 + i;
        pb[i] = *reinterpret_cast<const float4*>(&W[(size_t)(n0 + (f >> 3)) * DMM + k0 + 32 + ((f & 7) << 2)]);
      }
    }
    #pragma unroll
    for (int kk = 0; kk < 32; ++kk) {
      const float4 b4 = *reinterpret_cast<const float4*>(&Bs[kk][tx * 4]);
      #pragma unroll
      for (int r4 = 0; r4 < RM / 4; ++r4) {
        const float4 a4 = *reinterpret_cast<const float4*>(&As[kk][ty * RM + r4 * 4]);
        const int i0 = r4 * 4;
        acc[i0+0][0] += a4.x * b4.x; acc[i0+0][1] += a4.x * b4.y; acc[i0+0][2] += a4.x * b4.z; acc[i0+0][3] += a4.x * b4.w;
        acc[i0+1][0] += a4.y * b4.x; acc[i0+1][1] += a4.y * b4.y; acc[i0+1][2] += a4.y * b4.z; acc[i0+1][3] += a4.y * b4.w;
        acc[i0+2][0] += a4.z * b4.x; acc[i0+2][1] += a4.z * b4.y; acc[i0+2][2] += a4.z * b4.z; acc[i0+2][3] += a4.z * b4.w;
        acc[i0+3][0] += a4.w * b4.x; acc[i0+3][1] += a4.w * b4.y; acc[i0+3][2] += a4.w * b4.z; acc[i0+3][3] += a4.w * b4.w;
      }
    }
    __syncthreads();
  }

  const int n = n0 + tx * 4;
  const float4 b4 = *reinterpret_cast<const float4*>(&bias[n]);
  #pragma unroll
  for (int i = 0; i < RM; ++i) {
    const int m = m0 + ty * RM + i;
    float4 o;
    o.x = acc[i][0] + b4.x; o.y = acc[i][1] + b4.y;
    o.z = acc[i][2] + b4.z; o.w = acc[i][3] + b4.w;
    if (HEADS) {
      const int b = m >> 9;
      const int s = m & (SS - 1);
      const int h = n >> 5;
      const int d = n & (DFF - 1);
      *reinterpret_cast<float4*>(&Y[(((size_t)b * HH + h) * SS + s) * DFF + d]) = o;
    } else {
      *reinterpret_cast<float4*>(&Y[(size_t)m * DMM + n]) = o;
    }
  }
}

// q/k/v projections in one launch (blockIdx.z selects); q and k both use Wk.
__global__ __launch_bounds__(256) void proj_kernel(
    const float* __restrict__ q, const float* __restrict__ k, const float* __restrict__ v,
    const float* __restrict__ Wk, const float* __restrict__ bk,
    const float* __restrict__ Wv, const float* __restrict__ bv,
    float* __restrict__ qh, float* __restrict__ kh, float* __restrict__ vh)
{
  const int z = blockIdx.z;
  const float* X = (z == 0) ? q : (z == 1) ? k : v;
  const float* W = (z == 2) ? Wv : Wk;
  const float* bias = (z == 2) ? bv : bk;
  float* Y = (z == 0) ? qh : (z == 1) ? kh : vh;
  gemm_body<128, true>(X, W, bias, Y);
}

__global__ __launch_bounds__(256) void out_kernel(
    const float* __restrict__ X, const float* __restrict__ Wo,
    const float* __restrict__ bo, float* __restrict__ Y)
{
  gemm_body<64, false>(X, Wo, bo, Y);
}

// ---------------------------------------------------------------------------
// Attention: block = 4 waves = 4 consecutive qrows of one (b,h).
// K chunk (64 cols x 32 d) in LDS as [col][granule(16B)] with rotation
// swizzle phys_g=(g+col)&7 (same bijection on write & read): staging is
// 2x ds_write_b128/thread, QK^T is 8x ds_read_b128/lane, even bank spread.
// Softmax f32 with __expf (monotone; selection is ordering-based).
// Top-5 threshold: per-lane Batcher sort-8 -> sorted top-5, then 6-step
// butterfly merge of sorted-5 lists (order-statistic min/max identity).
// thr = exact 5th-largest value (multiset, = lax.top_k), m1 = exact max.
// ---------------------------------------------------------------------------
__global__ __launch_bounds__(256) void attn_kernel(
    const float* __restrict__ qh,
    const float* __restrict__ kh,
    const float* __restrict__ vh,
    const int* __restrict__ zp,
    float* __restrict__ attn,
    float* __restrict__ concat)
{
  __shared__ float4 Ksh[64 * 8];     // [col][granule], swizzled
  __shared__ float ws_w[4][8];
  __shared__ int   ws_c[4][8];

  const int tid  = threadIdx.x;
  const int lane = tid & 63;
  const int wave = tid >> 6;
  const int grp  = blockIdx.x;        // 0..16383
  const int bh   = grp >> 7;
  const int base = (grp & 127) << 2;
  const int qrow = base + wave;
  const int b    = bh >> 3;
  const int h    = bh & 7;
  const int ncols = qrow + 1;
  const float scale = 0.17677669529663688f;  // 1/sqrt(32)

  const float* kb = kh + (size_t)bh * SS * DFF;
  const float* vb = vh + (size_t)bh * SS * DFF;

  // q row into registers as 8 float4 granules
  float4 q4[8];
  {
    const float* qp = qh + ((size_t)bh * SS + qrow) * DFF;
    #pragma unroll
    for (int g = 0; g < 8; ++g)
      q4[g] = *reinterpret_cast<const float4*>(qp + g * 4);
  }

  const int nch  = ((base + 3) >> 6) + 1;
  const int mych = qrow >> 6;

  // staging: thread handles col=scol, granules g0,g0+1
  const int scol = tid & 63;
  const int g0   = (tid >> 6) << 1;

  float p[8];
  #pragma unroll
  for (int i = 0; i < 8; ++i) p[i] = -INFINITY;

  const float* kp0 = kb + (size_t)scol * DFF + g0 * 4;
  float4 r0 = *reinterpret_cast<const float4*>(kp0);
  float4 r1 = *reinterpret_cast<const float4*>(kp0 + 4);

  for (int c = 0; c < nch; ++c) {
    Ksh[(scol << 3) + ((g0 + scol) & 7)]     = r0;
    Ksh[(scol << 3) + ((g0 + 1 + scol) & 7)] = r1;
    __syncthreads();
    if (c + 1 < nch) {
      const float* kp = kb + (size_t)(((c + 1) << 6) + scol) * DFF + g0 * 4;
      r0 = *reinterpret_cast<const float4*>(kp);
      r1 = *reinterpret_cast<const float4*>(kp + 4);
    }
    if (c <= mych) {
      const int col = (c << 6) + lane;
      float d0 = 0.f, d1 = 0.f;
      #pragma unroll
      for (int g = 0; g < 8; ++g) {
        const int pg = (g + lane) & 7;
        const float4 kv = Ksh[(lane << 3) + pg];
        const float4 qv = q4[g];
        d0 = fmaf(qv.x, kv.x, d0);
        d1 = fmaf(qv.y, kv.y, d1);
        d0 = fmaf(qv.z, kv.z, d0);
        d1 = fmaf(qv.w, kv.w, d1);
      }
      if (col < ncols) p[c] = (d0 + d1) * scale;
    }
    __syncthreads();
  }

  // ---- softmax (f32; __expf is monotone, ~1e-7 rel) ----
  float m = p[0];
  #pragma unroll
  for (int s2 = 1; s2 < 8; ++s2) m = fmaxf(m, p[s2]);
  #pragma unroll
  for (int off = 32; off >= 1; off >>= 1) m = fmaxf(m, __shfl_xor(m, off, 64));
  float sum = 0.f;
  #pragma unroll
  for (int s2 = 0; s2 < 8; ++s2) {
    const float e = (p[s2] == -INFINITY) ? 0.f : __expf(p[s2] - m);
    p[s2] = e;
    sum += e;
  }
  #pragma unroll
  for (int off = 32; off >= 1; off >>= 1) sum += __shfl_xor(sum, off, 64);
  const float inv = 1.0f / sum;
  #pragma unroll
  for (int s2 = 0; s2 < 8; ++s2) p[s2] *= inv;

  // ---- top-5 threshold + re-softmax ----
  float neww[8];
  if (qrow > KIDX) {
    float v[8];
    #pragma unroll
    for (int s2 = 0; s2 < 8; ++s2) {
      const int col = lane + (s2 << 6);
      v[s2] = (col < ncols) ? p[s2] : -INFINITY;
    }
    // Batcher odd-even mergesort of 8, descending (19 compare-exchanges)
    #define CE(i, j) { const float t = fmaxf(v[i], v[j]); v[j] = fminf(v[i], v[j]); v[i] = t; }
    CE(0,1) CE(2,3) CE(4,5) CE(6,7)
    CE(0,2) CE(1,3) CE(4,6) CE(5,7)
    CE(1,2) CE(5,6)
    CE(0,4) CE(1,5) CE(2,6) CE(3,7)
    CE(2,4) CE(3,5)
    CE(1,2) CE(3,4) CE(5,6)
    #undef CE
    float a0 = v[0], a1 = v[1], a2 = v[2], a3 = v[3], a4 = v[4];
    #pragma unroll
    for (int off = 1; off <= 32; off <<= 1) {
      const float b0 = __shfl_xor(a0, off, 64);
      const float b1 = __shfl_xor(a1, off, 64);
      const float b2 = __shfl_xor(a2, off, 64);
      const float b3 = __shfl_xor(a3, off, 64);
      const float b4 = __shfl_xor(a4, off, 64);
      // merged[i] = max(a_i, b_i, max_{j+k=i-1} min(a_j,b_k))
      const float n0 = fmaxf(a0, b0);
      const float n1 = fmaxf(fmaxf(a1, b1), fminf(a0, b0));
      const float n2 = fmaxf(fmaxf(a2, b2), fmaxf(fminf(a0, b1), fminf(a1, b0)));
      const float n3 = fmaxf(fmaxf(a3, b3),
                       fmaxf(fmaxf(fminf(a0, b2), fminf(a1, b1)), fminf(a2, b0)));
      const float n4 = fmaxf(fmaxf(a4, b4),
                       fmaxf(fmaxf(fminf(a0, b3), fminf(a1, b2)),
                             fmaxf(fminf(a2, b1), fminf(a3, b0))));
      a0 = n0; a1 = n1; a2 = n2; a3 = n3; a4 = n4;
    }
    const float m1 = a0;     // exact max p (same value as jnp max)
    const float thr = a4;    // exact 5th-largest p (multiset semantics)
    float nsum = 0.f;
    #pragma unroll
    for (int s2 = 0; s2 < 8; ++s2) {
      const int col = lane + (s2 << 6);
      float e = 0.f;
      if (col < ncols && (p[s2] - thr >= 0.f)) e = __expf(p[s2] - m1);
      neww[s2] = e;
      nsum += e;
    }
    #pragma unroll
    for (int off = 32; off >= 1; off >>= 1) nsum += __shfl_xor(nsum, off, 64);
    const float ninv = 1.0f / nsum;
    #pragma unroll
    for (int s2 = 0; s2 < 8; ++s2) neww[s2] *= ninv;
  } else {
    #pragma unroll
    for (int s2 = 0; s2 < 8; ++s2) neww[s2] = p[s2];
  }

  if (qrow == 0 && *zp != 0) {
    #pragma unroll
    for (int s2 = 0; s2 < 8; ++s2) neww[s2] = 0.f;
  }

  // write full attn row
  {
    float* arow = attn + ((size_t)bh * SS + qrow) * SS;
    #pragma unroll
    for (int s2 = 0; s2 < 8; ++s2) arow[lane + (s2 << 6)] = neww[s2];
  }

  // ---- PV: rank kept columns into per-wave LDS, then parallel loads ----
  {
    unsigned long long msks[8];
    #pragma unroll
    for (int s2 = 0; s2 < 8; ++s2) msks[s2] = __ballot(neww[s2] != 0.f);
    int rbase = 0;
    #pragma unroll
    for (int s2 = 0; s2 < 8; ++s2) {
      const unsigned long long msk = msks[s2];
      const int myr = rbase + __popcll(msk & ((1ull << lane) - 1ull));
      if (((msk >> lane) & 1ull) && myr < 8) {
        ws_w[wave][myr] = neww[s2];
        ws_c[wave][myr] = (s2 << 6) | lane;
      }
      rbase += __popcll(msk);
    }
    const int nk = rbase;
    if (lane < 8 && lane >= nk) { ws_w[wave][lane] = 0.f; ws_c[wave][lane] = 0; }

    const int dd = lane & 31;
    float accv = 0.f;
    if (nk <= 8) {
      #pragma unroll
      for (int i = 0; i < 8; ++i)
        accv += ws_w[wave][i] * vb[(size_t)ws_c[wave][i] * DFF + dd];
    } else {
      // tie-overflow fallback (practically never taken)
      #pragma unroll
      for (int s2 = 0; s2 < 8; ++s2) {
        unsigned long long msk = msks[s2];
        while (msk) {
          const int src = __ffsll(msk) - 1;
          msk &= msk - 1;
          accv += __shfl(neww[s2], src, 64) * vb[(size_t)(src + (s2 << 6)) * DFF + dd];
        }
      }
    }
    if (lane < 32)
      concat[((size_t)b * SS + qrow) * DMM + h * DFF + dd] = accv;
  }
}

extern "C" void kernel_launch(void* const* d_in, const int* in_sizes, int n_in,
                              void* d_out, int out_size, void* d_ws, size_t ws_size,
                              hipStream_t stream) {
  const float* q  = (const float*)d_in[0];
  const float* k  = (const float*)d_in[1];
  const float* v  = (const float*)d_in[2];
  const int*   zp = (const int*)d_in[4];
  const float* Wk = (const float*)d_in[5];
  const float* bk = (const float*)d_in[6];
  const float* Wv = (const float*)d_in[7];
  const float* bv = (const float*)d_in[8];
  const float* Wo = (const float*)d_in[9];
  const float* bo = (const float*)d_in[10];

  float* ws     = (float*)d_ws;
  float* qhp    = ws;                 // (B,H,S,DF)
  float* khp    = ws + 2097152;       // (B,H,S,DF)
  float* vhp    = ws + 4194304;       // (B,H,S,DF)
  float* concat = ws + 6291456;       // (B,S,DM)

  float* outp  = (float*)d_out;                       // (B,S,DM)
  float* attnp = outp + (size_t)BB * SS * DMM;        // (B,H,S,S)

  proj_kernel<<<dim3(64, 4, 3), 256, 0, stream>>>(q, k, v, Wk, bk, Wv, bv, qhp, khp, vhp);
  attn_kernel<<<dim3(BB * HH * SS / 4), 256, 0, stream>>>(qhp, khp, vhp, zp, attnp, concat);
  out_kernel<<<dim3(128, 4), 256, 0, stream>>>(concat, Wo, bo, outp);
}

// Round 5
// 324.926 us; speedup vs baseline: 1.7163x; 1.0271x over previous
//
#include <hip/hip_runtime.h>
#include <hip/hip_bf16.h>
#include <math.h>

#define BB 16
#define SS 512
#define DMM 256
#define HH 8
#define DFF 32
#define KIDX 5

// ---------------------------------------------------------------------------
// GEMM: Y = X @ W^T + bias. X:(M,256), W:(256,256) row-major (N,K).
// TM x TN tile, 256 threads (16x16), per-thread (GM*4)x(GN*4) in split-4
// fragment groups (group gm at rows gm*TM/2 + ty*4 .. +3) -> fragment b128
// reads are 16B-stride across lanes = conflict-free. BK=16, reg prefetch.
// K accumulated sequentially 0..255 (bit-identical to prior passing rounds).
// ---------------------------------------------------------------------------
template<int TM, int TN, int GM, int GN, bool HEADS>
__device__ __forceinline__ void gemm_body(
    const float* __restrict__ X, const float* __restrict__ W,
    const float* __restrict__ bias, float* __restrict__ Y)
{
  __shared__ float As[16][TM];
  __shared__ float Bs[16][TN];
  constexpr int NA = TM / 64;
  constexpr int NB = TN / 64;
  const int tid = threadIdx.x;
  const int tx = tid & 15;
  const int ty = tid >> 4;
  const int m0 = blockIdx.x * TM;
  const int n0 = blockIdx.y * TN;

  float4 pa[NA], pb[NB];
  #pragma unroll
  for (int i = 0; i < NA; ++i) {
    const int f = tid * NA + i;
    pa[i] = *reinterpret_cast<const float4*>(&X[(size_t)(m0 + (f >> 2)) * DMM + ((f & 3) << 2)]);
  }
  #pragma unroll
  for (int i = 0; i < NB; ++i) {
    const int f = tid * NB + i;
    pb[i] = *reinterpret_cast<const float4*>(&W[(size_t)(n0 + (f >> 2)) * DMM + ((f & 3) << 2)]);
  }

  float acc[GM * 4][GN * 4] = {};

  for (int k0 = 0; k0 < DMM; k0 += 16) {
    #pragma unroll
    for (int i = 0; i < NA; ++i) {
      const int f = tid * NA + i;
      const int r = f >> 2, c4 = (f & 3) << 2;
      As[c4 + 0][r] = pa[i].x; As[c4 + 1][r] = pa[i].y;
      As[c4 + 2][r] = pa[i].z; As[c4 + 3][r] = pa[i].w;
    }
    #pragma unroll
    for (int i = 0; i < NB; ++i) {
      const int f = tid * NB + i;
      const int r = f >> 2, c4 = (f & 3) << 2;
      Bs[c4 + 0][r] = pb[i].x; Bs[c4 + 1][r] = pb[i].y;
      Bs[c4 + 2][r] = pb[i].z; Bs[c4 + 3][r] = pb[i].w;
    }
    __syncthreads();
    if (k0 + 16 < DMM) {
      #pragma unroll
      for (int i = 0; i < NA; ++i) {
        const int f = tid * NA + i;
        pa[i] = *reinterpret_cast<const float4*>(&X[(size_t)(m0 + (f >> 2)) * DMM + k0 + 16 + ((f & 3) << 2)]);
      }
      #pragma unroll
      for (int i = 0; i < NB; ++i) {
        const int f = tid * NB + i;
        pb[i] = *reinterpret_cast<const float4*>(&W[(size_t)(n0 + (f >> 2)) * DMM + k0 + 16 + ((f & 3) << 2)]);
      }
    }
    #pragma unroll
    for (int kk = 0; kk < 16; ++kk) {
      float4 af[GM], bf[GN];
      #pragma unroll
      for (int gm = 0; gm < GM; ++gm)
        af[gm] = *reinterpret_cast<const float4*>(&As[kk][gm * (TM / 2) + ty * 4]);
      #pragma unroll
      for (int gn = 0; gn < GN; ++gn)
        bf[gn] = *reinterpret_cast<const float4*>(&Bs[kk][gn * (TN / 2) + tx * 4]);
      #pragma unroll
      for (int gm = 0; gm < GM; ++gm) {
        const float am[4] = {af[gm].x, af[gm].y, af[gm].z, af[gm].w};
        #pragma unroll
        for (int i = 0; i < 4; ++i) {
          #pragma unroll
          for (int gn = 0; gn < GN; ++gn) {
            acc[gm*4+i][gn*4+0] = fmaf(am[i], bf[gn].x, acc[gm*4+i][gn*4+0]);
            acc[gm*4+i][gn*4+1] = fmaf(am[i], bf[gn].y, acc[gm*4+i][gn*4+1]);
            acc[gm*4+i][gn*4+2] = fmaf(am[i], bf[gn].z, acc[gm*4+i][gn*4+2]);
            acc[gm*4+i][gn*4+3] = fmaf(am[i], bf[gn].w, acc[gm*4+i][gn*4+3]);
          }
        }
      }
    }
    __syncthreads();
  }

  #pragma unroll
  for (int gn = 0; gn < GN; ++gn) {
    const int n = n0 + gn * (TN / 2) + tx * 4;
    const float4 b4 = *reinterpret_cast<const float4*>(&bias[n]);
    #pragma unroll
    for (int gm = 0; gm < GM; ++gm) {
      #pragma unroll
      for (int i = 0; i < 4; ++i) {
        const int m = m0 + gm * (TM / 2) + ty * 4 + i;
        float4 o;
        o.x = acc[gm*4+i][gn*4+0] + b4.x;
        o.y = acc[gm*4+i][gn*4+1] + b4.y;
        o.z = acc[gm*4+i][gn*4+2] + b4.z;
        o.w = acc[gm*4+i][gn*4+3] + b4.w;
        if (HEADS) {
          const int bb = m >> 9;
          const int s  = m & (SS - 1);
          const int hh = n >> 5;
          const int d  = n & (DFF - 1);
          *reinterpret_cast<float4*>(&Y[(((size_t)bb * HH + hh) * SS + s) * DFF + d]) = o;
        } else {
          *reinterpret_cast<float4*>(&Y[(size_t)m * DMM + n]) = o;
        }
      }
    }
  }
}

// q/k/v projections in one launch (blockIdx.z selects); q and k both use Wk.
__global__ __launch_bounds__(256) void proj_kernel(
    const float* __restrict__ q, const float* __restrict__ k, const float* __restrict__ v,
    const float* __restrict__ Wk, const float* __restrict__ bk,
    const float* __restrict__ Wv, const float* __restrict__ bv,
    float* __restrict__ qh, float* __restrict__ kh, float* __restrict__ vh)
{
  const int z = blockIdx.z;
  const float* X = (z == 0) ? q : (z == 1) ? k : v;
  const float* W = (z == 2) ? Wv : Wk;
  const float* bias = (z == 2) ? bv : bk;
  float* Y = (z == 0) ? qh : (z == 1) ? kh : vh;
  gemm_body<128, 128, 2, 2, true>(X, W, bias, Y);
}

__global__ __launch_bounds__(256) void out_kernel(
    const float* __restrict__ X, const float* __restrict__ Wo,
    const float* __restrict__ bo, float* __restrict__ Y)
{
  gemm_body<128, 64, 2, 1, false>(X, Wo, bo, Y);
}

// ---------------------------------------------------------------------------
// Attention row tail: softmax, top-5 (Batcher sort-8 + order-statistic
// butterfly merge of sorted-5 lists), re-softmax, zero_pad, attn-row write,
// sparse PV gather. Identical math/order to the passing R4 version.
// ---------------------------------------------------------------------------
__device__ __forceinline__ void attn_row_tail(
    float* p, const int qrow, const int lane,
    const int b, const int h, const int bh,
    const int* __restrict__ zp,
    float* __restrict__ attn, float* __restrict__ concat,
    const float* __restrict__ vb,
    float* wsw, int* wsc)
{
  const int ncols = qrow + 1;

  float m = p[0];
  #pragma unroll
  for (int s2 = 1; s2 < 8; ++s2) m = fmaxf(m, p[s2]);
  #pragma unroll
  for (int off = 32; off >= 1; off >>= 1) m = fmaxf(m, __shfl_xor(m, off, 64));
  float sum = 0.f;
  #pragma unroll
  for (int s2 = 0; s2 < 8; ++s2) {
    const float e = (p[s2] == -INFINITY) ? 0.f : __expf(p[s2] - m);
    p[s2] = e;
    sum += e;
  }
  #pragma unroll
  for (int off = 32; off >= 1; off >>= 1) sum += __shfl_xor(sum, off, 64);
  const float inv = 1.0f / sum;
  #pragma unroll
  for (int s2 = 0; s2 < 8; ++s2) p[s2] *= inv;

  float neww[8];
  if (qrow > KIDX) {
    float v[8];
    #pragma unroll
    for (int s2 = 0; s2 < 8; ++s2) {
      const int col = lane + (s2 << 6);
      v[s2] = (col < ncols) ? p[s2] : -INFINITY;
    }
    #define CE(i, j) { const float t = fmaxf(v[i], v[j]); v[j] = fminf(v[i], v[j]); v[i] = t; }
    CE(0,1) CE(2,3) CE(4,5) CE(6,7)
    CE(0,2) CE(1,3) CE(4,6) CE(5,7)
    CE(1,2) CE(5,6)
    CE(0,4) CE(1,5) CE(2,6) CE(3,7)
    CE(2,4) CE(3,5)
    CE(1,2) CE(3,4) CE(5,6)
    #undef CE
    float a0 = v[0], a1 = v[1], a2 = v[2], a3 = v[3], a4 = v[4];
    #pragma unroll
    for (int off = 1; off <= 32; off <<= 1) {
      const float b0 = __shfl_xor(a0, off, 64);
      const float b1 = __shfl_xor(a1, off, 64);
      const float b2 = __shfl_xor(a2, off, 64);
      const float b3 = __shfl_xor(a3, off, 64);
      const float b4 = __shfl_xor(a4, off, 64);
      const float n0 = fmaxf(a0, b0);
      const float n1 = fmaxf(fmaxf(a1, b1), fminf(a0, b0));
      const float n2 = fmaxf(fmaxf(a2, b2), fmaxf(fminf(a0, b1), fminf(a1, b0)));
      const float n3 = fmaxf(fmaxf(a3, b3),
                       fmaxf(fmaxf(fminf(a0, b2), fminf(a1, b1)), fminf(a2, b0)));
      const float n4 = fmaxf(fmaxf(a4, b4),
                       fmaxf(fmaxf(fminf(a0, b3), fminf(a1, b2)),
                             fmaxf(fminf(a2, b1), fminf(a3, b0))));
      a0 = n0; a1 = n1; a2 = n2; a3 = n3; a4 = n4;
    }
    const float m1 = a0;
    const float thr = a4;
    float nsum = 0.f;
    #pragma unroll
    for (int s2 = 0; s2 < 8; ++s2) {
      const int col = lane + (s2 << 6);
      float e = 0.f;
      if (col < ncols && (p[s2] - thr >= 0.f)) e = __expf(p[s2] - m1);
      neww[s2] = e;
      nsum += e;
    }
    #pragma unroll
    for (int off = 32; off >= 1; off >>= 1) nsum += __shfl_xor(nsum, off, 64);
    const float ninv = 1.0f / nsum;
    #pragma unroll
    for (int s2 = 0; s2 < 8; ++s2) neww[s2] *= ninv;
  } else {
    #pragma unroll
    for (int s2 = 0; s2 < 8; ++s2) neww[s2] = p[s2];
  }

  if (qrow == 0 && *zp != 0) {
    #pragma unroll
    for (int s2 = 0; s2 < 8; ++s2) neww[s2] = 0.f;
  }

  {
    float* arow = attn + ((size_t)bh * SS + qrow) * SS;
    #pragma unroll
    for (int s2 = 0; s2 < 8; ++s2) arow[lane + (s2 << 6)] = neww[s2];
  }

  {
    unsigned long long msks[8];
    #pragma unroll
    for (int s2 = 0; s2 < 8; ++s2) msks[s2] = __ballot(neww[s2] != 0.f);
    int rbase = 0;
    #pragma unroll
    for (int s2 = 0; s2 < 8; ++s2) {
      const unsigned long long msk = msks[s2];
      const int myr = rbase + __popcll(msk & ((1ull << lane) - 1ull));
      if (((msk >> lane) & 1ull) && myr < 8) {
        wsw[myr] = neww[s2];
        wsc[myr] = (s2 << 6) | lane;
      }
      rbase += __popcll(msk);
    }
    const int nk = rbase;
    if (lane < 8 && lane >= nk) { wsw[lane] = 0.f; wsc[lane] = 0; }

    const int dd = lane & 31;
    float accv = 0.f;
    if (nk <= 8) {
      #pragma unroll
      for (int i = 0; i < 8; ++i)
        accv += wsw[i] * vb[(size_t)wsc[i] * DFF + dd];
    } else {
      #pragma unroll
      for (int s2 = 0; s2 < 8; ++s2) {
        unsigned long long msk = msks[s2];
        while (msk) {
          const int src = __ffsll(msk) - 1;
          msk &= msk - 1;
          accv += __shfl(neww[s2], src, 64) * vb[(size_t)(src + (s2 << 6)) * DFF + dd];
        }
      }
    }
    if (lane < 32)
      concat[((size_t)b * SS + qrow) * DMM + h * DFF + dd] = accv;
  }
}

// ---------------------------------------------------------------------------
// Attention: block = 4 waves x 2 rows = 8 consecutive qrows of one (b,h).
// Wave w handles rows base+w and base+w+4 (same chunk range). Each staged
// K chunk b128-read ONCE per lane feeds BOTH rows' dot products -> LDS read
// traffic halved vs 1 row/wave. K chunk in LDS as [col][granule] with
// rotation swizzle phys_g=(g+col)&7 (same bijection write & read).
// ---------------------------------------------------------------------------
__global__ __launch_bounds__(256) void attn_kernel(
    const float* __restrict__ qh,
    const float* __restrict__ kh,
    const float* __restrict__ vh,
    const int* __restrict__ zp,
    float* __restrict__ attn,
    float* __restrict__ concat)
{
  __shared__ float4 Ksh[64 * 8];     // [col][granule], swizzled
  __shared__ float ws_w[4][8];
  __shared__ int   ws_c[4][8];

  const int tid  = threadIdx.x;
  const int lane = tid & 63;
  const int wave = tid >> 6;
  const int grp  = blockIdx.x;        // 0..8191
  const int bh   = grp >> 6;          // 64 row-groups of 8 per (b,h)
  const int base = (grp & 63) << 3;
  const int rA   = base + wave;
  const int rB   = rA + 4;
  const int b    = bh >> 3;
  const int h    = bh & 7;
  const float scale = 0.17677669529663688f;  // 1/sqrt(32)

  const float* kb = kh + (size_t)bh * SS * DFF;
  const float* vb = vh + (size_t)bh * SS * DFF;

  float4 qA[8], qB[8];
  {
    const float* qpA = qh + ((size_t)bh * SS + rA) * DFF;
    const float* qpB = qh + ((size_t)bh * SS + rB) * DFF;
    #pragma unroll
    for (int g = 0; g < 8; ++g) {
      qA[g] = *reinterpret_cast<const float4*>(qpA + g * 4);
      qB[g] = *reinterpret_cast<const float4*>(qpB + g * 4);
    }
  }

  // rows base..base+7 share the same last chunk (base % 8 == 0)
  const int nch = (base >> 6) + 1;

  const int scol = tid & 63;
  const int g0   = (tid >> 6) << 1;

  float pA[8], pB[8];
  #pragma unroll
  for (int i = 0; i < 8; ++i) { pA[i] = -INFINITY; pB[i] = -INFINITY; }

  const float* kp0 = kb + (size_t)scol * DFF + g0 * 4;
  float4 r0 = *reinterpret_cast<const float4*>(kp0);
  float4 r1 = *reinterpret_cast<const float4*>(kp0 + 4);

  for (int c = 0; c < nch; ++c) {
    Ksh[(scol << 3) + ((g0 + scol) & 7)]     = r0;
    Ksh[(scol << 3) + ((g0 + 1 + scol) & 7)] = r1;
    __syncthreads();
    if (c + 1 < nch) {
      const float* kp = kb + (size_t)(((c + 1) << 6) + scol) * DFF + g0 * 4;
      r0 = *reinterpret_cast<const float4*>(kp);
      r1 = *reinterpret_cast<const float4*>(kp + 4);
    }
    {
      const int col = (c << 6) + lane;
      float d0A = 0.f, d1A = 0.f, d0B = 0.f, d1B = 0.f;
      #pragma unroll
      for (int g = 0; g < 8; ++g) {
        const float4 kv = Ksh[(lane << 3) + ((g + lane) & 7)];
        const float4 qa = qA[g];
        const float4 qb = qB[g];
        d0A = fmaf(qa.x, kv.x, d0A);
        d1A = fmaf(qa.y, kv.y, d1A);
        d0A = fmaf(qa.z, kv.z, d0A);
        d1A = fmaf(qa.w, kv.w, d1A);
        d0B = fmaf(qb.x, kv.x, d0B);
        d1B = fmaf(qb.y, kv.y, d1B);
        d0B = fmaf(qb.z, kv.z, d0B);
        d1B = fmaf(qb.w, kv.w, d1B);
      }
      if (col <= rA) pA[c] = (d0A + d1A) * scale;
      if (col <= rB) pB[c] = (d0B + d1B) * scale;
    }
    __syncthreads();
  }

  attn_row_tail(pA, rA, lane, b, h, bh, zp, attn, concat, vb, ws_w[wave], ws_c[wave]);
  attn_row_tail(pB, rB, lane, b, h, bh, zp, attn, concat, vb, ws_w[wave], ws_c[wave]);
}

extern "C" void kernel_launch(void* const* d_in, const int* in_sizes, int n_in,
                              void* d_out, int out_size, void* d_ws, size_t ws_size,
                              hipStream_t stream) {
  const float* q  = (const float*)d_in[0];
  const float* k  = (const float*)d_in[1];
  const float* v  = (const float*)d_in[2];
  const int*   zp = (const int*)d_in[4];
  const float* Wk = (const float*)d_in[5];
  const float* bk = (const float*)d_in[6];
  const float* Wv = (const float*)d_in[7];
  const float* bv = (const float*)d_in[8];
  const float* Wo = (const float*)d_in[9];
  const float* bo = (const float*)d_in[10];

  float* ws     = (float*)d_ws;
  float* qhp    = ws;                 // (B,H,S,DF)
  float* khp    = ws + 2097152;       // (B,H,S,DF)
  float* vhp    = ws + 4194304;       // (B,H,S,DF)
  float* concat = ws + 6291456;       // (B,S,DM)

  float* outp  = (float*)d_out;                       // (B,S,DM)
  float* attnp = outp + (size_t)BB * SS * DMM;        // (B,H,S,S)

  proj_kernel<<<dim3(64, 2, 3), 256, 0, stream>>>(q, k, v, Wk, bk, Wv, bv, qhp, khp, vhp);
  attn_kernel<<<dim3(BB * HH * SS / 8), 256, 0, stream>>>(qhp, khp, vhp, zp, attnp, concat);
  out_kernel<<<dim3(64, 4), 256, 0, stream>>>(concat, Wo, bo, outp);
}